// Round 1
// baseline (549.992 us; speedup 1.0000x reference)
//
#include <hip/hip_runtime.h>
#include <math.h>

#define Q 256
#define H 256
#define ATTN_K 64
#define CAP 4096
#define HIST_BINS 65536

__device__ __forceinline__ unsigned f2k(float f) {
    unsigned u = __float_as_uint(f);
    return u ^ ((u & 0x80000000u) ? 0xFFFFFFFFu : 0x80000000u);
}

// ---------------- init: zero hist + state ----------------
__global__ void k_init(unsigned* __restrict__ hist, unsigned* __restrict__ state) {
    int i = blockIdx.x * blockDim.x + threadIdx.x;
    if (i < HIST_BINS) hist[i] = 0u;
    if (i < 16) state[i] = 0u;
}

// ---------------- GRU gate dots: one wave per output row o in [0,768) ----------------
__global__ void k_gru_gates(const float* __restrict__ question, const float* __restrict__ score,
                            const float* __restrict__ hs, const float* __restrict__ W_ih,
                            const float* __restrict__ W_hh, const float* __restrict__ b_ih,
                            const float* __restrict__ b_hh, float* __restrict__ gx,
                            float* __restrict__ gh, int N) {
    const int lane = threadIdx.x & 63;
    const int o = (blockIdx.x * blockDim.x + threadIdx.x) >> 6;
    if (o >= 3 * H) return;
    const int off = (score[0] >= 0.5f) ? 0 : Q;   // only one half of x is nonzero
    const float4 q = *reinterpret_cast<const float4*>(question + lane * 4);
    const float4 h = *reinterpret_cast<const float4*>(hs + (size_t)(N - 1) * H + lane * 4);
    const float4 wx = *reinterpret_cast<const float4*>(W_ih + (size_t)o * (2 * Q) + off + lane * 4);
    const float4 wh = *reinterpret_cast<const float4*>(W_hh + (size_t)o * H + lane * 4);
    float px = wx.x * q.x + wx.y * q.y + wx.z * q.z + wx.w * q.w;
    float ph = wh.x * h.x + wh.y * h.y + wh.z * h.z + wh.w * h.w;
#pragma unroll
    for (int d = 32; d > 0; d >>= 1) {
        px += __shfl_xor(px, d, 64);
        ph += __shfl_xor(ph, d, 64);
    }
    if (lane == 0) {
        gx[o] = px + b_ih[o];
        gh[o] = ph + b_hh[o];
    }
}

// ---------------- alpha matvec + 16-bit-key histogram ----------------
__global__ void k_alpha(const float* __restrict__ questions, const float* __restrict__ question,
                        float* __restrict__ alpha, unsigned* __restrict__ hist, int N) {
    const int lane = threadIdx.x & 63;
    const int wid = (blockIdx.x * blockDim.x + threadIdx.x) >> 6;
    const int nw = (gridDim.x * blockDim.x) >> 6;
    const float4 q = *reinterpret_cast<const float4*>(question + lane * 4);
    for (int r = wid; r < N; r += nw) {
        const float4 x = *reinterpret_cast<const float4*>(questions + (size_t)r * Q + lane * 4);
        float p = x.x * q.x + x.y * q.y + x.z * q.z + x.w * q.w;
#pragma unroll
        for (int d = 32; d > 0; d >>= 1) p += __shfl_xor(p, d, 64);
        if (lane == 0) {
            alpha[r] = p;
            atomicAdd(&hist[f2k(p) >> 16], 1u);
        }
    }
}

// ---------------- scan histogram: find threshold bin t1 (max bin with cum-from-top >= 64) ----------------
__global__ void k_scan(const unsigned* __restrict__ hist, unsigned* __restrict__ state) {
    __shared__ unsigned part[256];
    __shared__ unsigned cum[256];
    __shared__ unsigned seg[256];
    __shared__ unsigned suf[256];
    __shared__ int s_sh;
    __shared__ int tt_sh;
    const int t = threadIdx.x;

    // segment s covers bins [(255-s)*256, (255-s)*256+255]; s ascending = descending key order
    {
        unsigned sum = 0;
        const int base = (255 - t) * 256;
        for (int i = 0; i < 256; ++i) sum += hist[base + i];
        part[t] = sum;
    }
    __syncthreads();
    // inclusive prefix over segments (s ascending)
    cum[t] = part[t];
    __syncthreads();
    for (int d = 1; d < 256; d <<= 1) {
        unsigned add = (t >= d) ? cum[t - d] : 0u;
        __syncthreads();
        if (t >= d) cum[t] += add;
        __syncthreads();
    }
    if (t == 0) s_sh = 255;
    __syncthreads();
    if (cum[t] >= (unsigned)ATTN_K && (t == 0 || cum[t - 1] < (unsigned)ATTN_K)) s_sh = t;
    __syncthreads();
    const int s = s_sh;
    const unsigned before = (s > 0) ? cum[s - 1] : 0u;
    const int sbase = (255 - s) * 256;
    seg[t] = hist[sbase + t];
    __syncthreads();
    // suffix sum within segment (cum from high bins down)
    suf[t] = seg[t];
    __syncthreads();
    for (int d = 1; d < 256; d <<= 1) {
        unsigned add = (t + d < 256) ? suf[t + d] : 0u;
        __syncthreads();
        if (t + d < 256) suf[t] += add;
        __syncthreads();
    }
    if (t == 0) tt_sh = 0;
    __syncthreads();
    {
        bool ok = (before + suf[t]) >= (unsigned)ATTN_K;
        bool nok = (t + 1 < 256) ? ((before + suf[t + 1]) >= (unsigned)ATTN_K) : false;
        if (ok && !nok) tt_sh = t;
    }
    __syncthreads();
    if (t == 0) state[0] = (unsigned)(sbase + tt_sh);
}

// ---------------- collect candidates with key16 >= t1 ----------------
__global__ void k_collect(const float* __restrict__ alpha, const unsigned* __restrict__ state,
                          float* __restrict__ cval, int* __restrict__ cidx,
                          unsigned* __restrict__ count, int N) {
    const unsigned t1 = state[0];
    const int stride = gridDim.x * blockDim.x;
    for (int i = blockIdx.x * blockDim.x + threadIdx.x; i < N; i += stride) {
        float a = alpha[i];
        if ((f2k(a) >> 16) >= t1) {
            unsigned p = atomicAdd(count, 1u);
            if (p < CAP) { cval[p] = a; cidx[p] = i; }
        }
    }
}

// ---------------- head: exact top-64, softmax, attn, pred, GRU combine ----------------
__global__ void k_head(const float* __restrict__ question, const float* __restrict__ hs,
                       const float* __restrict__ W_score, const float* __restrict__ b_score,
                       const unsigned* __restrict__ state, const float* __restrict__ cval,
                       const int* __restrict__ cidx, const float* __restrict__ gx,
                       const float* __restrict__ gh, float* __restrict__ out, int N) {
    __shared__ float lv[CAP];
    __shared__ int li[CAP];
    __shared__ float sw[ATTN_K];
    __shared__ int si[ATTN_K];
    __shared__ float red[256];
    const int t = threadIdx.x;
    const int C = min((int)state[1], CAP);

    for (int i = t; i < C; i += 256) { lv[i] = cval[i]; li[i] = cidx[i]; }
    __syncthreads();

    // exact top-64 extraction by wave 0; ties -> lowest index (matches lax.top_k)
    if (t < 64) {
        for (int k = 0; k < ATTN_K; ++k) {
            float bv = -INFINITY;
            int bi = 0x7fffffff;
            int bp = -1;
            for (int i = t; i < C; i += 64) {
                float v = lv[i];
                int id = li[i];
                if (v > bv || (v == bv && id < bi)) { bv = v; bi = id; bp = i; }
            }
#pragma unroll
            for (int d = 32; d > 0; d >>= 1) {
                float ov = __shfl_xor(bv, d, 64);
                int oi = __shfl_xor(bi, d, 64);
                int op = __shfl_xor(bp, d, 64);
                if (ov > bv || (ov == bv && oi < bi)) { bv = ov; bi = oi; bp = op; }
            }
            if (t == 0) {
                sw[k] = bv;
                si[k] = bi;
                if (bp >= 0) lv[bp] = -INFINITY;
            }
        }
        // softmax over the 64 selected (sw[0] is the max: sorted descending)
        float m = sw[0];
        float e = expf(sw[t] - m);
        float ssum = e;
#pragma unroll
        for (int d = 32; d > 0; d >>= 1) ssum += __shfl_xor(ssum, d, 64);
        sw[t] = e / ssum;
    }
    __syncthreads();

    // attn_h[j], j = t in [0,256)
    float aj = 0.f;
    for (int k = 0; k < ATTN_K; ++k) {
        aj = fmaf(sw[k], hs[(size_t)si[k] * H + t], aj);
    }

    // pred = W_score[:256].question + W_score[256:].attn_h + b_score
    red[t] = W_score[t] * question[t] + W_score[Q + t] * aj;
    __syncthreads();
    for (int d = 128; d > 0; d >>= 1) {
        if (t < d) red[t] += red[t + d];
        __syncthreads();
    }
    if (t == 0) out[0] = red[0] + b_score[0];

    // GRU combine
    {
        float xr = gx[t], xz = gx[H + t], xn = gx[2 * H + t];
        float hr = gh[t], hz = gh[H + t], hn = gh[2 * H + t];
        float r = 1.f / (1.f + expf(-(xr + hr)));
        float z = 1.f / (1.f + expf(-(xz + hz)));
        float n = tanhf(xn + r * hn);
        float hprev = hs[(size_t)(N - 1) * H + t];
        out[1 + t] = (1.f - z) * n + z * hprev;
    }
}

extern "C" void kernel_launch(void* const* d_in, const int* in_sizes, int n_in,
                              void* d_out, int out_size, void* d_ws, size_t ws_size,
                              hipStream_t stream) {
    const float* question = (const float*)d_in[0];
    const float* score    = (const float*)d_in[1];
    const float* questions= (const float*)d_in[2];
    const float* hs       = (const float*)d_in[3];
    const float* W_score  = (const float*)d_in[4];
    const float* b_score  = (const float*)d_in[5];
    const float* W_ih     = (const float*)d_in[6];
    const float* W_hh     = (const float*)d_in[7];
    const float* b_ih     = (const float*)d_in[8];
    const float* b_hh     = (const float*)d_in[9];
    const int N = in_sizes[2] / Q;
    float* out = (float*)d_out;

    char* ws = (char*)d_ws;
    size_t off = 0;
    float* alpha = (float*)(ws + off); off += (size_t)N * sizeof(float);
    off = (off + 255) & ~(size_t)255;
    unsigned* hist = (unsigned*)(ws + off); off += (size_t)HIST_BINS * sizeof(unsigned);
    unsigned* state = (unsigned*)(ws + off); off += 256;      // [0]=t1 bin, [1]=cand count
    float* cval = (float*)(ws + off); off += (size_t)CAP * sizeof(float);
    int* cidx = (int*)(ws + off); off += (size_t)CAP * sizeof(int);
    float* gx = (float*)(ws + off); off += 3 * H * sizeof(float);
    float* gh = (float*)(ws + off); off += 3 * H * sizeof(float);

    k_init<<<HIST_BINS / 256, 256, 0, stream>>>(hist, state);
    k_gru_gates<<<(3 * H * 64) / 256, 256, 0, stream>>>(question, score, hs, W_ih, W_hh,
                                                        b_ih, b_hh, gx, gh, N);
    k_alpha<<<1024, 256, 0, stream>>>(questions, question, alpha, hist, N);
    k_scan<<<1, 256, 0, stream>>>(hist, state);
    k_collect<<<1024, 256, 0, stream>>>(alpha, state, cval, cidx, state + 1, N);
    k_head<<<1, 256, 0, stream>>>(question, hs, W_score, b_score, state, cval, cidx,
                                  gx, gh, out, N);
}

// Round 2
// 528.953 us; speedup vs baseline: 1.0398x; 1.0398x over previous
//
#include <hip/hip_runtime.h>
#include <math.h>

#define Q 256
#define H 256
#define ATTN_K 64
#define CAP 4096
#define HIST_BINS 65536

__device__ __forceinline__ unsigned f2k(float f) {
    unsigned u = __float_as_uint(f);
    return u ^ ((u & 0x80000000u) ? 0xFFFFFFFFu : 0x80000000u);
}

// ---------------- setup: zero hist+state, GRU gate dots (one wave per row o) ----------------
__global__ void k_setup(const float* __restrict__ question, const float* __restrict__ score,
                        const float* __restrict__ hs, const float* __restrict__ W_ih,
                        const float* __restrict__ W_hh, const float* __restrict__ b_ih,
                        const float* __restrict__ b_hh, float* __restrict__ gx,
                        float* __restrict__ gh, unsigned* __restrict__ hist,
                        unsigned* __restrict__ state, int N) {
    const int t = threadIdx.x;
    hist[blockIdx.x * 256 + t] = 0u;
    if (blockIdx.x == 255 && t < 16) state[t] = 0u;

    const int o = blockIdx.x * 4 + (t >> 6);      // blocks 0..191 cover o in [0,768)
    if (o >= 3 * H) return;
    const int lane = t & 63;
    const int off = (score[0] >= 0.5f) ? 0 : Q;   // only one half of x is nonzero
    const float4 q = *reinterpret_cast<const float4*>(question + lane * 4);
    const float4 h = *reinterpret_cast<const float4*>(hs + (size_t)(N - 1) * H + lane * 4);
    const float4 wx = *reinterpret_cast<const float4*>(W_ih + (size_t)o * (2 * Q) + off + lane * 4);
    const float4 wh = *reinterpret_cast<const float4*>(W_hh + (size_t)o * H + lane * 4);
    float px = wx.x * q.x + wx.y * q.y + wx.z * q.z + wx.w * q.w;
    float ph = wh.x * h.x + wh.y * h.y + wh.z * h.z + wh.w * h.w;
#pragma unroll
    for (int d = 32; d > 0; d >>= 1) {
        px += __shfl_xor(px, d, 64);
        ph += __shfl_xor(ph, d, 64);
    }
    if (lane == 0) {
        gx[o] = px + b_ih[o];
        gh[o] = ph + b_hh[o];
    }
}

// ---------------- alpha matvec: 16 lanes/row, 8 rows per wave-iteration ----------------
__global__ __launch_bounds__(256) void k_alpha(const float* __restrict__ questions,
                                               const float* __restrict__ question,
                                               float* __restrict__ alpha,
                                               unsigned* __restrict__ hist, int N) {
    const int lane = threadIdx.x & 63;
    const int sub  = lane & 15;       // 16 lanes per row
    const int rg   = lane >> 4;       // row within group of 4
    const int wid  = (blockIdx.x * blockDim.x + threadIdx.x) >> 6;
    const int nw   = (gridDim.x * blockDim.x) >> 6;

    float4 q[4];
#pragma unroll
    for (int j = 0; j < 4; ++j)
        q[j] = *reinterpret_cast<const float4*>(question + j * 64 + sub * 4);

    for (int g = wid; g * 8 < N; g += nw) {
        const int rA = g * 8 + rg;
        const int rB = rA + 4;
        float pA = 0.f, pB = 0.f;
        if (rA < N) {
            const float* rowA = questions + (size_t)rA * Q + sub * 4;
#pragma unroll
            for (int j = 0; j < 4; ++j) {
                float4 x = *reinterpret_cast<const float4*>(rowA + j * 64);
                pA = fmaf(x.x, q[j].x, fmaf(x.y, q[j].y, fmaf(x.z, q[j].z, fmaf(x.w, q[j].w, pA))));
            }
        }
        if (rB < N) {
            const float* rowB = questions + (size_t)rB * Q + sub * 4;
#pragma unroll
            for (int j = 0; j < 4; ++j) {
                float4 x = *reinterpret_cast<const float4*>(rowB + j * 64);
                pB = fmaf(x.x, q[j].x, fmaf(x.y, q[j].y, fmaf(x.z, q[j].z, fmaf(x.w, q[j].w, pB))));
            }
        }
#pragma unroll
        for (int d = 1; d < 16; d <<= 1) {
            pA += __shfl_xor(pA, d, 64);
            pB += __shfl_xor(pB, d, 64);
        }
        if (sub == 0) {
            if (rA < N) { alpha[rA] = pA; atomicAdd(&hist[f2k(pA) >> 16], 1u); }
            if (rB < N) { alpha[rB] = pB; atomicAdd(&hist[f2k(pB) >> 16], 1u); }
        }
    }
}

// ---------------- scan histogram: find threshold bin t1 ----------------
__global__ void k_scan(const unsigned* __restrict__ hist, unsigned* __restrict__ state) {
    __shared__ unsigned part[256];
    __shared__ unsigned cum[256];
    __shared__ unsigned seg[256];
    __shared__ unsigned suf[256];
    __shared__ int s_sh;
    __shared__ int tt_sh;
    const int t = threadIdx.x;

    {
        const uint4* hp = reinterpret_cast<const uint4*>(hist);
        unsigned sum = 0;
        const int base = (255 - t) * 64;
        for (int i = 0; i < 64; ++i) {
            uint4 v = hp[base + i];
            sum += v.x + v.y + v.z + v.w;
        }
        part[t] = sum;
    }
    __syncthreads();
    cum[t] = part[t];
    __syncthreads();
    for (int d = 1; d < 256; d <<= 1) {
        unsigned add = (t >= d) ? cum[t - d] : 0u;
        __syncthreads();
        if (t >= d) cum[t] += add;
        __syncthreads();
    }
    if (t == 0) s_sh = 255;
    __syncthreads();
    if (cum[t] >= (unsigned)ATTN_K && (t == 0 || cum[t - 1] < (unsigned)ATTN_K)) s_sh = t;
    __syncthreads();
    const int s = s_sh;
    const unsigned before = (s > 0) ? cum[s - 1] : 0u;
    const int sbase = (255 - s) * 256;
    seg[t] = hist[sbase + t];
    __syncthreads();
    suf[t] = seg[t];
    __syncthreads();
    for (int d = 1; d < 256; d <<= 1) {
        unsigned add = (t + d < 256) ? suf[t + d] : 0u;
        __syncthreads();
        if (t + d < 256) suf[t] += add;
        __syncthreads();
    }
    if (t == 0) tt_sh = 0;
    __syncthreads();
    {
        bool ok = (before + suf[t]) >= (unsigned)ATTN_K;
        bool nok = (t + 1 < 256) ? ((before + suf[t + 1]) >= (unsigned)ATTN_K) : false;
        if (ok && !nok) tt_sh = t;
    }
    __syncthreads();
    if (t == 0) state[0] = (unsigned)(sbase + tt_sh);
}

// ---------------- collect candidates with key16 >= t1 (float4 sweep) ----------------
__global__ void k_collect(const float* __restrict__ alpha, const unsigned* __restrict__ state,
                          float* __restrict__ cval, int* __restrict__ cidx,
                          unsigned* __restrict__ count, int N) {
    const unsigned t1 = state[0];
    const int stride = gridDim.x * blockDim.x;
    const int n4 = N >> 2;
    const float4* a4 = reinterpret_cast<const float4*>(alpha);
    for (int i = blockIdx.x * blockDim.x + threadIdx.x; i < n4; i += stride) {
        float4 a = a4[i];
        float v[4] = {a.x, a.y, a.z, a.w};
#pragma unroll
        for (int j = 0; j < 4; ++j) {
            if ((f2k(v[j]) >> 16) >= t1) {
                unsigned p = atomicAdd(count, 1u);
                if (p < CAP) { cval[p] = v[j]; cidx[p] = i * 4 + j; }
            }
        }
    }
}

// ---------------- head: exact top-64, softmax, attn, pred, GRU combine ----------------
__global__ void k_head(const float* __restrict__ question, const float* __restrict__ hs,
                       const float* __restrict__ W_score, const float* __restrict__ b_score,
                       const unsigned* __restrict__ state, const float* __restrict__ cval,
                       const int* __restrict__ cidx, const float* __restrict__ gx,
                       const float* __restrict__ gh, float* __restrict__ out, int N) {
    __shared__ float lv[CAP];
    __shared__ int li[CAP];
    __shared__ float sw[ATTN_K];
    __shared__ int si[ATTN_K];
    __shared__ float red[256];
    const int t = threadIdx.x;
    const int C = min((int)state[1], CAP);

    for (int i = t; i < C; i += 256) { lv[i] = cval[i]; li[i] = cidx[i]; }
    __syncthreads();

    // exact top-64 extraction by wave 0; ties -> lowest index (matches lax.top_k)
    if (t < 64) {
        for (int k = 0; k < ATTN_K; ++k) {
            float bv = -INFINITY;
            int bi = 0x7fffffff;
            int bp = -1;
            for (int i = t; i < C; i += 64) {
                float v = lv[i];
                int id = li[i];
                if (v > bv || (v == bv && id < bi)) { bv = v; bi = id; bp = i; }
            }
#pragma unroll
            for (int d = 32; d > 0; d >>= 1) {
                float ov = __shfl_xor(bv, d, 64);
                int oi = __shfl_xor(bi, d, 64);
                int op = __shfl_xor(bp, d, 64);
                if (ov > bv || (ov == bv && oi < bi)) { bv = ov; bi = oi; bp = op; }
            }
            if (t == 0) {
                sw[k] = bv;
                si[k] = bi;
                if (bp >= 0) lv[bp] = -INFINITY;
            }
        }
        float m = sw[0];
        float e = expf(sw[t] - m);
        float ssum = e;
#pragma unroll
        for (int d = 32; d > 0; d >>= 1) ssum += __shfl_xor(ssum, d, 64);
        sw[t] = e / ssum;
    }
    __syncthreads();

    // attn_h[j], j = t in [0,256)
    float aj = 0.f;
    for (int k = 0; k < ATTN_K; ++k) {
        aj = fmaf(sw[k], hs[(size_t)si[k] * H + t], aj);
    }

    // pred
    red[t] = W_score[t] * question[t] + W_score[Q + t] * aj;
    __syncthreads();
    for (int d = 128; d > 0; d >>= 1) {
        if (t < d) red[t] += red[t + d];
        __syncthreads();
    }
    if (t == 0) out[0] = red[0] + b_score[0];

    // GRU combine
    {
        float xr = gx[t], xz = gx[H + t], xn = gx[2 * H + t];
        float hr = gh[t], hz = gh[H + t], hn = gh[2 * H + t];
        float r = 1.f / (1.f + expf(-(xr + hr)));
        float z = 1.f / (1.f + expf(-(xz + hz)));
        float n = tanhf(xn + r * hn);
        float hprev = hs[(size_t)(N - 1) * H + t];
        out[1 + t] = (1.f - z) * n + z * hprev;
    }
}

extern "C" void kernel_launch(void* const* d_in, const int* in_sizes, int n_in,
                              void* d_out, int out_size, void* d_ws, size_t ws_size,
                              hipStream_t stream) {
    const float* question = (const float*)d_in[0];
    const float* score    = (const float*)d_in[1];
    const float* questions= (const float*)d_in[2];
    const float* hs       = (const float*)d_in[3];
    const float* W_score  = (const float*)d_in[4];
    const float* b_score  = (const float*)d_in[5];
    const float* W_ih     = (const float*)d_in[6];
    const float* W_hh     = (const float*)d_in[7];
    const float* b_ih     = (const float*)d_in[8];
    const float* b_hh     = (const float*)d_in[9];
    const int N = in_sizes[2] / Q;
    float* out = (float*)d_out;

    char* ws = (char*)d_ws;
    size_t off = 0;
    float* alpha = (float*)(ws + off); off += (size_t)N * sizeof(float);
    off = (off + 255) & ~(size_t)255;
    unsigned* hist = (unsigned*)(ws + off); off += (size_t)HIST_BINS * sizeof(unsigned);
    unsigned* state = (unsigned*)(ws + off); off += 256;      // [0]=t1 bin, [1]=cand count
    float* cval = (float*)(ws + off); off += (size_t)CAP * sizeof(float);
    int* cidx = (int*)(ws + off); off += (size_t)CAP * sizeof(int);
    float* gx = (float*)(ws + off); off += 3 * H * sizeof(float);
    float* gh = (float*)(ws + off); off += 3 * H * sizeof(float);

    k_setup<<<256, 256, 0, stream>>>(question, score, hs, W_ih, W_hh, b_ih, b_hh,
                                     gx, gh, hist, state, N);
    k_alpha<<<2048, 256, 0, stream>>>(questions, question, alpha, hist, N);
    k_scan<<<1, 256, 0, stream>>>(hist, state);
    k_collect<<<512, 256, 0, stream>>>(alpha, state, cval, cidx, state + 1, N);
    k_head<<<1, 256, 0, stream>>>(question, hs, W_score, b_score, state, cval, cidx,
                                  gx, gh, out, N);
}

// Round 3
// 268.484 us; speedup vs baseline: 2.0485x; 1.9702x over previous
//
#include <hip/hip_runtime.h>
#include <math.h>

#define Q 256
#define H 256
#define ATTN_K 64
#define CAP 4096
#define HBINS 4096   // 13-bit key (sign+exp+5 mantissa bits), positives only

__device__ __forceinline__ unsigned f2k(float f) {
    unsigned u = __float_as_uint(f);
    return u ^ ((u & 0x80000000u) ? 0xFFFFFFFFu : 0x80000000u);
}

// ---------------- setup: zero hist+state, GRU gate dots (one wave per row o) ----------------
__global__ void k_setup(const float* __restrict__ question, const float* __restrict__ score,
                        const float* __restrict__ hs, const float* __restrict__ W_ih,
                        const float* __restrict__ W_hh, const float* __restrict__ b_ih,
                        const float* __restrict__ b_hh, float* __restrict__ gx,
                        float* __restrict__ gh, unsigned* __restrict__ hist,
                        unsigned* __restrict__ state, int N) {
    const int t = threadIdx.x;
    if (blockIdx.x < 16) hist[blockIdx.x * 256 + t] = 0u;
    if (blockIdx.x == 255 && t < 16) state[t] = 0u;

    const int o = blockIdx.x * 4 + (t >> 6);      // blocks 0..191 cover o in [0,768)
    if (o >= 3 * H) return;
    const int lane = t & 63;
    const int off = (score[0] >= 0.5f) ? 0 : Q;   // only one half of x is nonzero
    const float4 q = *reinterpret_cast<const float4*>(question + lane * 4);
    const float4 h = *reinterpret_cast<const float4*>(hs + (size_t)(N - 1) * H + lane * 4);
    const float4 wx = *reinterpret_cast<const float4*>(W_ih + (size_t)o * (2 * Q) + off + lane * 4);
    const float4 wh = *reinterpret_cast<const float4*>(W_hh + (size_t)o * H + lane * 4);
    float px = wx.x * q.x + wx.y * q.y + wx.z * q.z + wx.w * q.w;
    float ph = wh.x * h.x + wh.y * h.y + wh.z * h.z + wh.w * h.w;
#pragma unroll
    for (int d = 32; d > 0; d >>= 1) {
        px += __shfl_xor(px, d, 64);
        ph += __shfl_xor(ph, d, 64);
    }
    if (lane == 0) {
        gx[o] = px + b_ih[o];
        gh[o] = ph + b_hh[o];
    }
}

// ---------------- alpha matvec: PURE streaming, no atomics ----------------
__global__ __launch_bounds__(256) void k_alpha(const float* __restrict__ questions,
                                               const float* __restrict__ question,
                                               float* __restrict__ alpha, int N) {
    const int lane = threadIdx.x & 63;
    const int sub  = lane & 15;       // 16 lanes per row
    const int rg   = lane >> 4;       // row within group of 4
    const int wid  = (blockIdx.x * blockDim.x + threadIdx.x) >> 6;
    const int nw   = (gridDim.x * blockDim.x) >> 6;

    float4 q[4];
#pragma unroll
    for (int j = 0; j < 4; ++j)
        q[j] = *reinterpret_cast<const float4*>(question + j * 64 + sub * 4);

    for (int g = wid; g * 8 < N; g += nw) {
        const int rA = g * 8 + rg;
        const int rB = rA + 4;
        float pA = 0.f, pB = 0.f;
        if (rA < N) {
            const float* rowA = questions + (size_t)rA * Q + sub * 4;
#pragma unroll
            for (int j = 0; j < 4; ++j) {
                float4 x = *reinterpret_cast<const float4*>(rowA + j * 64);
                pA = fmaf(x.x, q[j].x, fmaf(x.y, q[j].y, fmaf(x.z, q[j].z, fmaf(x.w, q[j].w, pA))));
            }
        }
        if (rB < N) {
            const float* rowB = questions + (size_t)rB * Q + sub * 4;
#pragma unroll
            for (int j = 0; j < 4; ++j) {
                float4 x = *reinterpret_cast<const float4*>(rowB + j * 64);
                pB = fmaf(x.x, q[j].x, fmaf(x.y, q[j].y, fmaf(x.z, q[j].z, fmaf(x.w, q[j].w, pB))));
            }
        }
#pragma unroll
        for (int d = 1; d < 16; d <<= 1) {
            pA += __shfl_xor(pA, d, 64);
            pB += __shfl_xor(pB, d, 64);
        }
        if (sub == 0) {
            if (rA < N) alpha[rA] = pA;
            if (rB < N) alpha[rB] = pB;
        }
    }
}

// ---------------- histogram of alpha with per-block LDS hist (13-bit key, positives) ----------------
__global__ __launch_bounds__(1024) void k_hist(const float* __restrict__ alpha,
                                               unsigned* __restrict__ hist, int N) {
    __shared__ unsigned hb[HBINS];
    const int t = threadIdx.x;
#pragma unroll
    for (int j = 0; j < HBINS / 1024; ++j) hb[t + j * 1024] = 0u;
    __syncthreads();

    const int n4 = N >> 2;
    const int stride = gridDim.x * blockDim.x;
    const float4* a4 = reinterpret_cast<const float4*>(alpha);
    for (int i = blockIdx.x * blockDim.x + t; i < n4; i += stride) {
        float4 a = a4[i];
        float v[4] = {a.x, a.y, a.z, a.w};
#pragma unroll
        for (int j = 0; j < 4; ++j) {
            int rel = (int)(f2k(v[j]) >> 19) - 4096;   // positives land in [0,4095]
            if (rel >= 0) atomicAdd(&hb[rel], 1u);
        }
    }
    // scalar tail (N not multiple of 4)
    if (blockIdx.x == 0 && t < (N & 3)) {
        float v = alpha[(n4 << 2) + t];
        int rel = (int)(f2k(v) >> 19) - 4096;
        if (rel >= 0) atomicAdd(&hb[rel], 1u);
    }
    __syncthreads();
#pragma unroll
    for (int j = 0; j < HBINS / 1024; ++j) {
        unsigned v = hb[t + j * 1024];
        if (v) atomicAdd(&hist[t + j * 1024], v);
    }
}

// ---------------- scan 4096-bin hist: threshold key13 with cum-from-top >= 64 ----------------
__global__ __launch_bounds__(1024) void k_scan(const unsigned* __restrict__ hist,
                                               unsigned* __restrict__ state) {
    __shared__ unsigned part[1024];
    __shared__ unsigned cum[1024];
    __shared__ int s_sh;
    const int t = threadIdx.x;

    {   // segment t covers bins [4092-4t .. 4095-4t] (t ascending = descending keys)
        const int hi = 4095 - 4 * t;
        part[t] = hist[hi] + hist[hi - 1] + hist[hi - 2] + hist[hi - 3];
    }
    __syncthreads();
    cum[t] = part[t];
    __syncthreads();
    for (int d = 1; d < 1024; d <<= 1) {
        unsigned add = (t >= d) ? cum[t - d] : 0u;
        __syncthreads();
        if (t >= d) cum[t] += add;
        __syncthreads();
    }
    if (t == 0) s_sh = 1023;
    __syncthreads();
    if (cum[t] >= (unsigned)ATTN_K && (t == 0 || cum[t - 1] < (unsigned)ATTN_K)) s_sh = t;
    __syncthreads();
    if (t == 0) {
        const int s = s_sh;
        unsigned acc = (s > 0) ? cum[s - 1] : 0u;
        const int hi = 4095 - 4 * s;
        int tb = hi - 3;
        for (int b = hi; b >= hi - 3; --b) {
            acc += hist[b];
            if (acc >= (unsigned)ATTN_K) { tb = b; break; }
        }
        state[0] = (unsigned)(tb + 4096);   // absolute 13-bit key threshold
    }
}

// ---------------- collect candidates with key13 >= tau ----------------
__global__ void k_collect(const float* __restrict__ alpha, const unsigned* __restrict__ state,
                          float* __restrict__ cval, int* __restrict__ cidx,
                          unsigned* __restrict__ count, int N) {
    const int tau = (int)state[0];
    const int stride = gridDim.x * blockDim.x;
    const int n4 = N >> 2;
    const float4* a4 = reinterpret_cast<const float4*>(alpha);
    for (int i = blockIdx.x * blockDim.x + threadIdx.x; i < n4; i += stride) {
        float4 a = a4[i];
        float v[4] = {a.x, a.y, a.z, a.w};
#pragma unroll
        for (int j = 0; j < 4; ++j) {
            if ((int)(f2k(v[j]) >> 19) >= tau) {
                unsigned p = atomicAdd(count, 1u);
                if (p < CAP) { cval[p] = v[j]; cidx[p] = i * 4 + j; }
            }
        }
    }
    if (blockIdx.x == 0 && threadIdx.x < (N & 3)) {
        const int idx = (n4 << 2) + threadIdx.x;
        float v = alpha[idx];
        if ((int)(f2k(v) >> 19) >= tau) {
            unsigned p = atomicAdd(count, 1u);
            if (p < CAP) { cval[p] = v; cidx[p] = idx; }
        }
    }
}

// ---------------- head: exact top-64, softmax, attn, pred, GRU combine ----------------
__global__ void k_head(const float* __restrict__ question, const float* __restrict__ hs,
                       const float* __restrict__ W_score, const float* __restrict__ b_score,
                       const unsigned* __restrict__ state, const float* __restrict__ cval,
                       const int* __restrict__ cidx, const float* __restrict__ gx,
                       const float* __restrict__ gh, float* __restrict__ out, int N) {
    __shared__ float lv[CAP];
    __shared__ int li[CAP];
    __shared__ float sw[ATTN_K];
    __shared__ int si[ATTN_K];
    __shared__ float red[256];
    const int t = threadIdx.x;
    const int C = min((int)state[1], CAP);

    for (int i = t; i < C; i += 256) { lv[i] = cval[i]; li[i] = cidx[i]; }
    __syncthreads();

    // exact top-64 extraction by wave 0; ties -> lowest index (matches lax.top_k)
    if (t < 64) {
        for (int k = 0; k < ATTN_K; ++k) {
            float bv = -INFINITY;
            int bi = 0x7fffffff;
            int bp = -1;
            for (int i = t; i < C; i += 64) {
                float v = lv[i];
                int id = li[i];
                if (v > bv || (v == bv && id < bi)) { bv = v; bi = id; bp = i; }
            }
#pragma unroll
            for (int d = 32; d > 0; d >>= 1) {
                float ov = __shfl_xor(bv, d, 64);
                int oi = __shfl_xor(bi, d, 64);
                int op = __shfl_xor(bp, d, 64);
                if (ov > bv || (ov == bv && oi < bi)) { bv = ov; bi = oi; bp = op; }
            }
            if (t == 0) {
                sw[k] = bv;
                si[k] = (bi == 0x7fffffff) ? 0 : bi;
                if (bp >= 0) lv[bp] = -INFINITY;
            }
        }
        float m = sw[0];
        float e = expf(sw[t] - m);
        float ssum = e;
#pragma unroll
        for (int d = 32; d > 0; d >>= 1) ssum += __shfl_xor(ssum, d, 64);
        sw[t] = e / ssum;
    }
    __syncthreads();

    // attn_h[j], j = t in [0,256)
    float aj = 0.f;
    for (int k = 0; k < ATTN_K; ++k) {
        aj = fmaf(sw[k], hs[(size_t)si[k] * H + t], aj);
    }

    // pred
    red[t] = W_score[t] * question[t] + W_score[Q + t] * aj;
    __syncthreads();
    for (int d = 128; d > 0; d >>= 1) {
        if (t < d) red[t] += red[t + d];
        __syncthreads();
    }
    if (t == 0) out[0] = red[0] + b_score[0];

    // GRU combine
    {
        float xr = gx[t], xz = gx[H + t], xn = gx[2 * H + t];
        float hr = gh[t], hz = gh[H + t], hn = gh[2 * H + t];
        float r = 1.f / (1.f + expf(-(xr + hr)));
        float z = 1.f / (1.f + expf(-(xz + hz)));
        float n = tanhf(xn + r * hn);
        float hprev = hs[(size_t)(N - 1) * H + t];
        out[1 + t] = (1.f - z) * n + z * hprev;
    }
}

extern "C" void kernel_launch(void* const* d_in, const int* in_sizes, int n_in,
                              void* d_out, int out_size, void* d_ws, size_t ws_size,
                              hipStream_t stream) {
    const float* question = (const float*)d_in[0];
    const float* score    = (const float*)d_in[1];
    const float* questions= (const float*)d_in[2];
    const float* hs       = (const float*)d_in[3];
    const float* W_score  = (const float*)d_in[4];
    const float* b_score  = (const float*)d_in[5];
    const float* W_ih     = (const float*)d_in[6];
    const float* W_hh     = (const float*)d_in[7];
    const float* b_ih     = (const float*)d_in[8];
    const float* b_hh     = (const float*)d_in[9];
    const int N = in_sizes[2] / Q;
    float* out = (float*)d_out;

    char* ws = (char*)d_ws;
    size_t off = 0;
    float* alpha = (float*)(ws + off); off += (size_t)N * sizeof(float);
    off = (off + 255) & ~(size_t)255;
    unsigned* hist = (unsigned*)(ws + off); off += (size_t)HBINS * sizeof(unsigned);
    unsigned* state = (unsigned*)(ws + off); off += 256;      // [0]=tau13, [1]=cand count
    float* cval = (float*)(ws + off); off += (size_t)CAP * sizeof(float);
    int* cidx = (int*)(ws + off); off += (size_t)CAP * sizeof(int);
    float* gx = (float*)(ws + off); off += 3 * H * sizeof(float);
    float* gh = (float*)(ws + off); off += 3 * H * sizeof(float);

    k_setup<<<256, 256, 0, stream>>>(question, score, hs, W_ih, W_hh, b_ih, b_hh,
                                     gx, gh, hist, state, N);
    k_alpha<<<2048, 256, 0, stream>>>(questions, question, alpha, N);
    k_hist<<<16, 1024, 0, stream>>>(alpha, hist, N);
    k_scan<<<1, 1024, 0, stream>>>(hist, state);
    k_collect<<<512, 256, 0, stream>>>(alpha, state, cval, cidx, state + 1, N);
    k_head<<<1, 256, 0, stream>>>(question, hs, W_score, b_score, state, cval, cidx,
                                  gx, gh, out, N);
}

// Round 4
// 238.343 us; speedup vs baseline: 2.3076x; 1.1265x over previous
//
#include <hip/hip_runtime.h>
#include <math.h>

#define Q 256
#define H 256
#define ATTN_K 64
#define CAP 4096
#define HBINS 4096   // 13-bit key (sign+exp+5 mantissa bits), positives only

typedef float f4 __attribute__((ext_vector_type(4)));

__device__ __forceinline__ unsigned f2k(float f) {
    unsigned u = __float_as_uint(f);
    return u ^ ((u & 0x80000000u) ? 0xFFFFFFFFu : 0x80000000u);
}

// ============ kernel 1: zero hist/state + GRU gate dots + alpha matvec ============
// state: [0]=tau13  [1]=cand count  [2]=collect arrive  [3]=hist arrive
__global__ __launch_bounds__(256) void k_main(const float* __restrict__ questions,
                                              const float* __restrict__ question,
                                              const float* __restrict__ score,
                                              const float* __restrict__ hs,
                                              const float* __restrict__ W_ih,
                                              const float* __restrict__ W_hh,
                                              const float* __restrict__ b_ih,
                                              const float* __restrict__ b_hh,
                                              float* __restrict__ gx, float* __restrict__ gh,
                                              unsigned* __restrict__ hist,
                                              unsigned* __restrict__ state,
                                              float* __restrict__ alpha, int N) {
    const int t = threadIdx.x;
    const int b = blockIdx.x;
    if (b < 16) hist[b * 256 + t] = 0u;
    if (b == 16 && t < 16) state[t] = 0u;

    const int lane = t & 63;
    const int wid = b * 4 + (t >> 6);

    // ---- GRU gate dots: first 768 waves, one output row each ----
    if (wid < 3 * H) {
        const int o = wid;
        const int off = (score[0] >= 0.5f) ? 0 : Q;
        const float4 q = *reinterpret_cast<const float4*>(question + lane * 4);
        const float4 h = *reinterpret_cast<const float4*>(hs + (size_t)(N - 1) * H + lane * 4);
        const float4 wx = *reinterpret_cast<const float4*>(W_ih + (size_t)o * (2 * Q) + off + lane * 4);
        const float4 wh = *reinterpret_cast<const float4*>(W_hh + (size_t)o * H + lane * 4);
        float px = wx.x * q.x + wx.y * q.y + wx.z * q.z + wx.w * q.w;
        float ph = wh.x * h.x + wh.y * h.y + wh.z * h.z + wh.w * h.w;
#pragma unroll
        for (int d = 32; d > 0; d >>= 1) {
            px += __shfl_xor(px, d, 64);
            ph += __shfl_xor(ph, d, 64);
        }
        if (lane == 0) {
            gx[o] = px + b_ih[o];
            gh[o] = ph + b_hh[o];
        }
    }

    // ---- alpha: 16 lanes/row, 8 rows per wave-iteration, nontemporal streams ----
    const int sub = lane & 15;
    const int rg  = lane >> 4;
    const int nw  = (gridDim.x * blockDim.x) >> 6;

    float4 q[4];
#pragma unroll
    for (int j = 0; j < 4; ++j)
        q[j] = *reinterpret_cast<const float4*>(question + j * 64 + sub * 4);

    const size_t stepRows = (size_t)nw * 8;
    const float* baseA = questions + (size_t)(wid * 8 + rg) * Q + sub * 4;
    for (size_t r0 = (size_t)wid * 8; r0 < (size_t)N; r0 += stepRows, baseA += stepRows * Q) {
        const int rA = (int)r0 + rg;
        const int rB = rA + 4;
        float pA = 0.f, pB = 0.f;
        if (rA < N) {
#pragma unroll
            for (int j = 0; j < 4; ++j) {
                f4 x = __builtin_nontemporal_load(reinterpret_cast<const f4*>(baseA + j * 64));
                pA = fmaf(x.x, q[j].x, fmaf(x.y, q[j].y, fmaf(x.z, q[j].z, fmaf(x.w, q[j].w, pA))));
            }
        }
        if (rB < N) {
#pragma unroll
            for (int j = 0; j < 4; ++j) {
                f4 x = __builtin_nontemporal_load(reinterpret_cast<const f4*>(baseA + 4 * Q + j * 64));
                pB = fmaf(x.x, q[j].x, fmaf(x.y, q[j].y, fmaf(x.z, q[j].z, fmaf(x.w, q[j].w, pB))));
            }
        }
#pragma unroll
        for (int d = 1; d < 16; d <<= 1) {
            pA += __shfl_xor(pA, d, 64);
            pB += __shfl_xor(pB, d, 64);
        }
        if (sub == 0) {
            if (rA < N) alpha[rA] = pA;
            if (rB < N) alpha[rB] = pB;
        }
    }
}

// ============ kernel 2: LDS histogram of alpha; last block scans for tau ============
__global__ __launch_bounds__(1024) void k_histscan(const float* __restrict__ alpha,
                                                   unsigned* __restrict__ hist,
                                                   unsigned* __restrict__ state, int N) {
    __shared__ unsigned hb[HBINS];
    __shared__ unsigned wsum[16];
    __shared__ int flag_sh;
    const int t = threadIdx.x;
#pragma unroll
    for (int j = 0; j < HBINS / 1024; ++j) hb[t + j * 1024] = 0u;
    __syncthreads();

    const int n4 = N >> 2;
    const int stride = gridDim.x * blockDim.x;
    const float4* a4 = reinterpret_cast<const float4*>(alpha);
    for (int i = blockIdx.x * blockDim.x + t; i < n4; i += stride) {
        float4 a = a4[i];
        float v[4] = {a.x, a.y, a.z, a.w};
#pragma unroll
        for (int j = 0; j < 4; ++j) {
            int rel = (int)(f2k(v[j]) >> 19) - 4096;
            if (rel >= 0) atomicAdd(&hb[rel], 1u);
        }
    }
    if (blockIdx.x == 0 && t < (N & 3)) {
        float v = alpha[(n4 << 2) + t];
        int rel = (int)(f2k(v) >> 19) - 4096;
        if (rel >= 0) atomicAdd(&hb[rel], 1u);
    }
    __syncthreads();
#pragma unroll
    for (int j = 0; j < HBINS / 1024; ++j) {
        unsigned v = hb[t + j * 1024];
        if (v) atomicAdd(&hist[t + j * 1024], v);
    }

    // ---- arrive; last block performs the scan ----
    if (t == 0) {
        __threadfence();
        unsigned a = atomicAdd(&state[3], 1u);
        flag_sh = (a == gridDim.x - 1) ? 1 : 0;
    }
    __syncthreads();
    if (!flag_sh) return;
    __threadfence();

    // part over 4 bins, descending keys: segment t covers bins [4092-4t .. 4095-4t]
    const uint4* h4 = reinterpret_cast<const uint4*>(hist);
    uint4 hv = h4[1023 - t];
    unsigned x = hv.x + hv.y + hv.z + hv.w;

    // inclusive scan: shfl within wave, then cross-wave
    const int lane = t & 63;
    const int w = t >> 6;
#pragma unroll
    for (int d = 1; d < 64; d <<= 1) {
        unsigned y = __shfl_up(x, d, 64);
        if (lane >= d) x += y;
    }
    if (lane == 63) wsum[w] = x;
    __syncthreads();
    if (w == 0 && lane < 16) {
        unsigned s = wsum[lane];
#pragma unroll
        for (int d = 1; d < 16; d <<= 1) {
            unsigned y = __shfl_up(s, d, 64);
            if (lane >= d) s += y;
        }
        wsum[lane] = s;
    }
    __syncthreads();
    unsigned cum = x + ((w > 0) ? wsum[w - 1] : 0u);
    hb[t] = cum;   // reuse hb as cum array
    __syncthreads();
    if (cum >= (unsigned)ATTN_K && (t == 0 || hb[t - 1] < (unsigned)ATTN_K)) {
        // unique boundary thread resolves the exact bin
        const int s = t;
        unsigned acc = (s > 0) ? hb[s - 1] : 0u;
        const int hi = 4095 - 4 * s;
        int tb = hi - 3;
        for (int bin = hi; bin >= hi - 3; --bin) {
            acc += hist[bin];
            if (acc >= (unsigned)ATTN_K) { tb = bin; break; }
        }
        state[0] = (unsigned)(tb + 4096);
    }
}

// ============ kernel 3: collect candidates; last block does head ============
__global__ __launch_bounds__(256) void k_collecthead(const float* __restrict__ alpha,
                                                     const float* __restrict__ question,
                                                     const float* __restrict__ hs,
                                                     const float* __restrict__ W_score,
                                                     const float* __restrict__ b_score,
                                                     unsigned* __restrict__ state,
                                                     float* __restrict__ cval, int* __restrict__ cidx,
                                                     const float* __restrict__ gx,
                                                     const float* __restrict__ gh,
                                                     float* __restrict__ out, int N) {
    __shared__ float lv[CAP];
    __shared__ int li[CAP];
    __shared__ float sw[ATTN_K];
    __shared__ int si[ATTN_K];
    __shared__ float red[256];
    __shared__ int flag_sh;
    const int t = threadIdx.x;
    const int tau = (int)state[0];

    {
        const int stride = gridDim.x * blockDim.x;
        const int n4 = N >> 2;
        const float4* a4 = reinterpret_cast<const float4*>(alpha);
        for (int i = blockIdx.x * blockDim.x + t; i < n4; i += stride) {
            float4 a = a4[i];
            float v[4] = {a.x, a.y, a.z, a.w};
#pragma unroll
            for (int j = 0; j < 4; ++j) {
                if ((int)(f2k(v[j]) >> 19) >= tau) {
                    unsigned p = atomicAdd(&state[1], 1u);
                    if (p < CAP) { cval[p] = v[j]; cidx[p] = i * 4 + j; }
                }
            }
        }
        if (blockIdx.x == 0 && t < (N & 3)) {
            const int idx = (n4 << 2) + t;
            float v = alpha[idx];
            if ((int)(f2k(v) >> 19) >= tau) {
                unsigned p = atomicAdd(&state[1], 1u);
                if (p < CAP) { cval[p] = v; cidx[p] = idx; }
            }
        }
    }

    if (t == 0) {
        __threadfence();
        unsigned a = atomicAdd(&state[2], 1u);
        flag_sh = (a == gridDim.x - 1) ? 1 : 0;
    }
    __syncthreads();
    if (!flag_sh) return;
    __threadfence();

    const int C = min((int)state[1], CAP);
    for (int i = t; i < C; i += 256) { lv[i] = cval[i]; li[i] = cidx[i]; }
    __syncthreads();

    // exact top-64 by wave 0; ties -> lowest index (matches lax.top_k)
    if (t < 64) {
        for (int k = 0; k < ATTN_K; ++k) {
            float bv = -INFINITY;
            int bi = 0x7fffffff;
            int bp = -1;
            for (int i = t; i < C; i += 64) {
                float v = lv[i];
                int id = li[i];
                if (v > bv || (v == bv && id < bi)) { bv = v; bi = id; bp = i; }
            }
#pragma unroll
            for (int d = 32; d > 0; d >>= 1) {
                float ov = __shfl_xor(bv, d, 64);
                int oi = __shfl_xor(bi, d, 64);
                int op = __shfl_xor(bp, d, 64);
                if (ov > bv || (ov == bv && oi < bi)) { bv = ov; bi = oi; bp = op; }
            }
            if (t == 0) {
                sw[k] = bv;
                si[k] = (bi == 0x7fffffff) ? 0 : bi;
                if (bp >= 0) lv[bp] = -INFINITY;
            }
        }
        float m = sw[0];
        float e = expf(sw[t] - m);
        float ssum = e;
#pragma unroll
        for (int d = 32; d > 0; d >>= 1) ssum += __shfl_xor(ssum, d, 64);
        sw[t] = e / ssum;
    }
    __syncthreads();

    // attn_h[j]
    float aj = 0.f;
    for (int k = 0; k < ATTN_K; ++k) {
        aj = fmaf(sw[k], hs[(size_t)si[k] * H + t], aj);
    }

    // pred
    red[t] = W_score[t] * question[t] + W_score[Q + t] * aj;
    __syncthreads();
    for (int d = 128; d > 0; d >>= 1) {
        if (t < d) red[t] += red[t + d];
        __syncthreads();
    }
    if (t == 0) out[0] = red[0] + b_score[0];

    // GRU combine
    {
        float xr = gx[t], xz = gx[H + t], xn = gx[2 * H + t];
        float hr = gh[t], hz = gh[H + t], hn = gh[2 * H + t];
        float r = 1.f / (1.f + expf(-(xr + hr)));
        float z = 1.f / (1.f + expf(-(xz + hz)));
        float n = tanhf(xn + r * hn);
        float hprev = hs[(size_t)(N - 1) * H + t];
        out[1 + t] = (1.f - z) * n + z * hprev;
    }
}

extern "C" void kernel_launch(void* const* d_in, const int* in_sizes, int n_in,
                              void* d_out, int out_size, void* d_ws, size_t ws_size,
                              hipStream_t stream) {
    const float* question = (const float*)d_in[0];
    const float* score    = (const float*)d_in[1];
    const float* questions= (const float*)d_in[2];
    const float* hs       = (const float*)d_in[3];
    const float* W_score  = (const float*)d_in[4];
    const float* b_score  = (const float*)d_in[5];
    const float* W_ih     = (const float*)d_in[6];
    const float* W_hh     = (const float*)d_in[7];
    const float* b_ih     = (const float*)d_in[8];
    const float* b_hh     = (const float*)d_in[9];
    const int N = in_sizes[2] / Q;
    float* out = (float*)d_out;

    char* ws = (char*)d_ws;
    size_t off = 0;
    float* alpha = (float*)(ws + off); off += (size_t)N * sizeof(float);
    off = (off + 255) & ~(size_t)255;
    unsigned* hist = (unsigned*)(ws + off); off += (size_t)HBINS * sizeof(unsigned);
    unsigned* state = (unsigned*)(ws + off); off += 256;
    float* cval = (float*)(ws + off); off += (size_t)CAP * sizeof(float);
    int* cidx = (int*)(ws + off); off += (size_t)CAP * sizeof(int);
    float* gx = (float*)(ws + off); off += 3 * H * sizeof(float);
    float* gh = (float*)(ws + off); off += 3 * H * sizeof(float);

    k_main<<<2048, 256, 0, stream>>>(questions, question, score, hs, W_ih, W_hh,
                                     b_ih, b_hh, gx, gh, hist, state, alpha, N);
    k_histscan<<<64, 1024, 0, stream>>>(alpha, hist, state, N);
    k_collecthead<<<512, 256, 0, stream>>>(alpha, question, hs, W_score, b_score,
                                           state, cval, cidx, gx, gh, out, N);
}